// Round 2
// baseline (1198.644 us; speedup 1.0000x reference)
//
#include <hip/hip_runtime.h>
#include <math.h>

#define VOCAB 400000
#define D 300
#define NF 256
#define TOPK 5
#define NS 200
#define LS 64
#define LQ 30
#define RS (NS*LS)      /* 12800 sentence rows */
#define RT (RS+LQ)      /* 12830 total rows (sents then question) */

/* ws layout (float offsets) */
#define OFF_ROWS 0
#define OFF_CONV (RT*D)                 /* 3,849,000 */
#define OFF_NE   (OFF_CONV + RT*NF)     /* emb norms */
#define OFF_NC   (OFF_NE + RT)          /* conv norms */
#define OFF_MK   (OFF_NC + RT)          /* mask (id>1) */
#define OFF_LO   (OFF_MK + RT)          /* lo[NS*LQ] */

/* ---------------- Kernel A: gather rows + emb norms + mask ---------------- */
__global__ void gather_kernel(const float* __restrict__ emb,
                              const int* __restrict__ question,
                              const int* __restrict__ sents,
                              float* __restrict__ ws) {
    int r = blockIdx.x;
    int lane = threadIdx.x;
    int idx = (r < RS) ? sents[r] : question[r - RS];
    const float* src = emb + (size_t)idx * D;
    float* dst = ws + OFF_ROWS + (size_t)r * D;
    float ss = 0.f;
    #pragma unroll
    for (int i = 0; i < 5; ++i) {
        int d = lane + i*64;
        if (d < D) { float v = src[d]; dst[d] = v; ss += v*v; }
    }
    #pragma unroll
    for (int off = 32; off; off >>= 1) ss += __shfl_xor(ss, off, 64);
    if (lane == 0) {
        ws[OFF_NE + r] = sqrtf(ss);
        ws[OFF_MK + r] = (idx > 1) ? 1.f : 0.f;
    }
}

/* ---------------- Kernel B: conv as shifted GEMM ----------------
   out[r][f] = sum_{k=0..2} [inseg(r,k)] sum_d rows[r+k][d] * filt[f*900+k*300+d]
   M=12830, N=256, K=900 in 15 chunks of 60 (k constant per chunk).
   Tile 128x64, 256 threads, 8x4 per thread. */
#define BM 128
#define BN 64
#define BK 60
__global__ __launch_bounds__(256)
void conv_gemm_kernel(const float* __restrict__ rows,
                      const float* __restrict__ filt,
                      float* __restrict__ conv) {
    __shared__ float As[BK*132];   /* [t][row], stride 132 (16B aligned, padded) */
    __shared__ float Bs[BK*66];    /* [t][f],   stride 66 */
    int m0 = blockIdx.x * BM;
    int f0 = blockIdx.y * BN;
    int tid = threadIdx.x;
    int tx = tid & 15, ty = tid >> 4;

    float acc[8][4];
    #pragma unroll
    for (int i = 0; i < 8; ++i)
        #pragma unroll
        for (int j = 0; j < 4; ++j) acc[i][j] = 0.f;

    for (int c = 0; c < 15; ++c) {
        int k = c / 5;
        int dbase = (c % 5) * 60;
        /* A tile: 128 rows x 60 k-slice, with sentence-boundary zeroing */
        #pragma unroll
        for (int j = 0; j < 30; ++j) {
            int pos = j*256 + tid;
            int row = pos / 60, t = pos - row*60;
            int gr = m0 + row;
            float v = 0.f;
            if (gr < RT) {
                bool ok = (gr < RS) ? (((gr & 63) + k) < LS) : ((gr + k) < RT);
                if (ok) v = rows[(gr + k)*D + dbase + t];
            }
            As[t*132 + row] = v;
        }
        /* B tile: 60 x 64 filters */
        #pragma unroll
        for (int j = 0; j < 15; ++j) {
            int pos = j*256 + tid;
            int fc = pos / 60, t = pos - fc*60;
            Bs[t*66 + fc] = filt[(f0 + fc)*900 + k*300 + dbase + t];
        }
        __syncthreads();
        #pragma unroll 4
        for (int t = 0; t < BK; ++t) {
            float a[8], b[4];
            *(float4*)&a[0] = *(const float4*)&As[t*132 + ty*8];
            *(float4*)&a[4] = *(const float4*)&As[t*132 + ty*8 + 4];
            *(float2*)&b[0] = *(const float2*)&Bs[t*66 + tx*4];
            *(float2*)&b[2] = *(const float2*)&Bs[t*66 + tx*4 + 2];
            #pragma unroll
            for (int i = 0; i < 8; ++i)
                #pragma unroll
                for (int j = 0; j < 4; ++j) acc[i][j] += a[i]*b[j];
        }
        __syncthreads();
    }
    #pragma unroll
    for (int i = 0; i < 8; ++i) {
        int gr = m0 + ty*8 + i;
        if (gr < RT) {
            #pragma unroll
            for (int j = 0; j < 4; ++j)
                conv[(size_t)gr*NF + f0 + tx*4 + j] = acc[i][j];
        }
    }
}

/* ---------------- Kernel C: conv row norms ---------------- */
__global__ void convnorm_kernel(const float* __restrict__ conv, float* __restrict__ ws) {
    int w = threadIdx.x >> 6, lane = threadIdx.x & 63;
    int r = blockIdx.x*4 + w;
    if (r >= RT) return;
    float ss = 0.f;
    #pragma unroll
    for (int i = 0; i < 4; ++i) {
        float v = conv[(size_t)r*NF + lane + i*64];
        ss += v*v;
    }
    #pragma unroll
    for (int off = 32; off; off >>= 1) ss += __shfl_xor(ss, off, 64);
    if (lane == 0) ws[OFF_NC + r] = sqrtf(ss);
}

/* ---------------- top-5 pool over 64 lanes ---------------- */
__device__ inline void pool64(float v, float& mx, float& mean5) {
    int lane = threadIdx.x & 63;
    float sum = 0.f;
    mx = 0.f;
    #pragma unroll
    for (int it = 0; it < TOPK; ++it) {
        float m = v; int ml = lane;
        #pragma unroll
        for (int off = 32; off; off >>= 1) {
            float ov = __shfl_xor(m, off, 64);
            int ol = __shfl_xor(ml, off, 64);
            if (ov > m || (ov == m && ol < ml)) { m = ov; ml = ol; }
        }
        if (it == 0) mx = m;
        sum += m;
        if (lane == ml) v = -INFINITY;
    }
    mean5 = sum * (1.f/TOPK);
}

/* ---------------- Kernel D: sims + pools + sigmoid ----------------
   grid (8, NS): block = (n, group of 4 q's), 4 waves, wave w owns q = qg*4+w.
   Lane = sentence position s. */
__global__ __launch_bounds__(256)
void sim_pool_kernel(const float* __restrict__ ws,
                     const float* __restrict__ dsim,
                     const float* __restrict__ lin_w,
                     const float* __restrict__ lin_b,
                     float* __restrict__ lo_out) {
    __shared__ float tile[64*66];
    __shared__ float qt[4*66];
    int qg = blockIdx.x, n = blockIdx.y;
    int tid = threadIdx.x;
    int w = tid >> 6, lane = tid & 63;
    int q = qg*4 + w;
    int qe = (q < LQ) ? q : (LQ-1);
    const float* rows = ws + OFF_ROWS;
    const float* conv = ws + OFF_CONV;

    float acc_i = 0.f, acc_s = 0.f;
    /* insens dots over D=300 in 5 chunks */
    for (int c = 0; c < 5; ++c) {
        int base = c*64;
        int len = (D - base < 64) ? (D - base) : 64;
        #pragma unroll
        for (int ii = 0; ii < 16; ++ii) {
            int row = ii*4 + w;
            tile[row*66 + lane] = (lane < len) ? rows[(n*LS + row)*D + base + lane] : 0.f;
        }
        qt[w*66 + lane] = (lane < len) ? rows[(RS + qe)*D + base + lane] : 0.f;
        __syncthreads();
        for (int d = 0; d < len; d += 2) {
            float2 tv = *(const float2*)&tile[lane*66 + d];
            float2 qv = *(const float2*)&qt[w*66 + d];
            acc_i += tv.x*qv.x + tv.y*qv.y;
        }
        __syncthreads();
    }
    /* sens dots over NF=256 in 4 chunks */
    for (int c = 0; c < 4; ++c) {
        int base = c*64;
        #pragma unroll
        for (int ii = 0; ii < 16; ++ii) {
            int row = ii*4 + w;
            tile[row*66 + lane] = conv[(size_t)(n*LS + row)*NF + base + lane];
        }
        qt[w*66 + lane] = conv[(size_t)(RS + qe)*NF + base + lane];
        __syncthreads();
        for (int d = 0; d < 64; d += 2) {
            float2 tv = *(const float2*)&tile[lane*66 + d];
            float2 qv = *(const float2*)&qt[w*66 + d];
            acc_s += tv.x*qv.x + tv.y*qv.y;
        }
        __syncthreads();
    }

    int sr = n*LS + lane;
    float ne_s = ws[OFF_NE + sr], ne_q = ws[OFF_NE + RS + qe];
    float nc_s = ws[OFF_NC + sr], nc_q = ws[OFF_NC + RS + qe];
    float mk   = ws[OFF_MK + sr] * ws[OFF_MK + RS + qe];
    float si = acc_i / (ne_q * ne_s) * mk;
    float sc = acc_s / (nc_q * nc_s);
    float so = dsim[(size_t)sr*LQ + qe];

    float f0,f1,f2,f3,f4,f5;
    pool64(si, f0, f1);
    pool64(sc, f2, f3);
    pool64(so, f4, f5);

    if (lane == 0 && q < LQ) {
        float z = lin_b[0]
                + f0*lin_w[0] + f1*lin_w[1]
                + f2*lin_w[2] + f3*lin_w[3]
                + f4*lin_w[4] + f5*lin_w[5];
        lo_out[n*LQ + q] = 1.f / (1.f + expf(-z));
    }
}

/* ---------------- Kernel E: means ---------------- */
__global__ void final_kernel(const float* __restrict__ lo, float* __restrict__ out) {
    __shared__ float red[256];
    int tid = threadIdx.x;
    float s = 0.f;
    if (tid < NS) {
        float a = 0.f;
        for (int q = 0; q < LQ; ++q) a += lo[tid*LQ + q];
        a *= (1.f/LQ);
        out[1 + tid] = a;
        s = a;
    }
    red[tid] = s;
    __syncthreads();
    for (int off = 128; off; off >>= 1) {
        if (tid < off) red[tid] += red[tid + off];
        __syncthreads();
    }
    if (tid == 0) out[0] = red[0] * (1.f/NS);
}

extern "C" void kernel_launch(void* const* d_in, const int* in_sizes, int n_in,
                              void* d_out, int out_size, void* d_ws, size_t ws_size,
                              hipStream_t stream) {
    const float* emb      = (const float*)d_in[0];
    const float* filt     = (const float*)d_in[1];
    const float* lin_w    = (const float*)d_in[2];
    const float* lin_b    = (const float*)d_in[3];
    const int*   question = (const int*)d_in[4];
    const int*   sents    = (const int*)d_in[5];
    const float* dsim     = (const float*)d_in[6];
    float* ws  = (float*)d_ws;
    float* out = (float*)d_out;

    gather_kernel<<<RT, 64, 0, stream>>>(emb, question, sents, ws);
    conv_gemm_kernel<<<dim3((RT + BM - 1)/BM, NF/BN), 256, 0, stream>>>(
        ws + OFF_ROWS, filt, ws + OFF_CONV);
    convnorm_kernel<<<(RT + 3)/4, 256, 0, stream>>>(ws + OFF_CONV, ws);
    sim_pool_kernel<<<dim3(8, NS), 256, 0, stream>>>(ws, dsim, lin_w, lin_b, ws + OFF_LO);
    final_kernel<<<1, 256, 0, stream>>>(ws + OFF_LO, out);
}

// Round 3
// 639.012 us; speedup vs baseline: 1.8758x; 1.8758x over previous
//
#include <hip/hip_runtime.h>
#include <math.h>

#define VOCAB 400000
#define D 300
#define NF 256
#define TOPK 5
#define NS 200
#define LS 64
#define LQ 30
#define RS (NS*LS)      /* 12800 sentence rows */
#define RT (RS+LQ)      /* 12830 real rows (sents then question) */
#define MP 12832        /* rows padded to 32 (2 zero rows after question) */
#define KQ 320          /* padded emb dim for MFMA (300 -> 320) */
#define KC3 960         /* conv GEMM K = 3*320 */

/* ws layout (float offsets). bf16 regions counted as elems/2 floats. */
#define F_ROWS16 0                          /* ushort[MP*320]  */
#define F_FILT16 (F_ROWS16 + (MP*KQ/2))    /* ushort[256*960] */
#define F_CONV16 (F_FILT16 + (NF*KC3/2))   /* ushort[MP*256]  */
#define F_NE     (F_CONV16 + (MP*NF/2))
#define F_NC     (F_NE + RT)
#define F_MK     (F_NC + RT)
#define F_DI     (F_MK + RT)                /* float[NS*32*64] */
#define F_DS     (F_DI + NS*32*64)
#define F_SENT   (F_DS + NS*32*64)

typedef __attribute__((ext_vector_type(8))) short bf16x8;
typedef __attribute__((ext_vector_type(4))) float f32x4;

__device__ inline ushort f2bf(float f) {
    union { float f; unsigned u; } x; x.f = f;
    unsigned r = x.u + 0x7fffu + ((x.u >> 16) & 1u);   /* RNE */
    return (ushort)(r >> 16);
}
__device__ inline float bf2f(ushort h) {
    union { unsigned u; float f; } x; x.u = ((unsigned)h) << 16; return x.f;
}

/* ---- Kernel 1: gather rows -> bf16 [MP][320], emb norms, mask ---- */
__global__ void gather16_kernel(const float* __restrict__ emb,
                                const int* __restrict__ question,
                                const int* __restrict__ sents,
                                float* __restrict__ ws) {
    int r = blockIdx.x;          /* 0..MP-1 */
    int lane = threadIdx.x;      /* 64 */
    ushort* rows16 = (ushort*)(ws + F_ROWS16) + (size_t)r * KQ;
    if (r >= RT) {               /* zero pad rows */
        #pragma unroll
        for (int i = 0; i < 5; ++i) rows16[lane + i*64] = 0;
        return;
    }
    int idx = (r < RS) ? sents[r] : question[r - RS];
    const float* src = emb + (size_t)idx * D;
    float ss = 0.f;
    #pragma unroll
    for (int i = 0; i < 5; ++i) {
        int d = lane + i*64;
        float v = (d < D) ? src[d] : 0.f;
        rows16[d] = f2bf(v);
        ss += v*v;
    }
    #pragma unroll
    for (int off = 32; off; off >>= 1) ss += __shfl_xor(ss, off, 64);
    if (lane == 0) {
        ws[F_NE + r] = sqrtf(ss);
        ws[F_MK + r] = (idx > 1) ? 1.f : 0.f;
    }
}

/* ---- Kernel 2: filters -> bf16 [256][960] (3 segs of 320, zero-padded) ---- */
__global__ void filt16_kernel(const float* __restrict__ filt, float* __restrict__ ws) {
    int f = blockIdx.x, lane = threadIdx.x;
    ushort* dst = (ushort*)(ws + F_FILT16) + (size_t)f * KC3;
    #pragma unroll
    for (int seg = 0; seg < 3; ++seg)
        #pragma unroll
        for (int i = 0; i < 5; ++i) {
            int d = lane + i*64;
            float v = (d < D) ? filt[f*900 + seg*300 + d] : 0.f;
            dst[seg*KQ + d] = f2bf(v);
        }
}

/* ---- Kernel 3: conv as bf16 MFMA GEMM, staged with shift (no im2col) ----
   out[r][f] = sum_seg [valid] sum_d rows[r+seg][d]*filt[f][seg][d]
   Tile 64x64, 4 waves each 32x32, BK=64 (2 MFMA k-chunks). */
__global__ __launch_bounds__(256)
void conv16_gemm_kernel(const float* __restrict__ ws_c, float* __restrict__ ws) {
    __shared__ ushort As[64*72];
    __shared__ ushort Bs[64*72];
    const ushort* rows16 = (const ushort*)(ws_c + F_ROWS16);
    const ushort* filt16 = (const ushort*)(ws_c + F_FILT16);
    ushort* conv16 = (ushort*)(ws + F_CONV16);
    int m0 = blockIdx.x * 64;
    int f0 = blockIdx.y * 64;
    int tid = threadIdx.x;
    int lane = tid & 63, w = tid >> 6;
    int srow = tid >> 3, sh = tid & 7;      /* staging: row 0..31? no: 256/8=32 rows per pass */
    int qm = (w & 1) * 32, fn = (w >> 1) * 32;

    f32x4 acc00 = {}, acc01 = {}, acc10 = {}, acc11 = {};

    for (int kt = 0; kt < 15; ++kt) {
        int seg = kt / 5;
        int dbase = (kt % 5) * 64;
        /* A: 64 rows x 64 bf16; 32 rows per half-pass (256 thr x 16B) */
        #pragma unroll
        for (int p = 0; p < 2; ++p) {
            int row = p*32 + srow;
            int gr = m0 + row;
            bool ok = (gr < RS) ? (((gr & 63) + seg) < LS) : ((gr + seg) < RT);
            uint4 val = make_uint4(0,0,0,0);
            if (ok) val = *(const uint4*)(rows16 + (size_t)(gr + seg)*KQ + dbase + sh*8);
            *(uint4*)&As[row*72 + sh*8] = val;
            /* B: 64 filter cols x 64 bf16 */
            int col = p*32 + srow;
            uint4 bv = *(const uint4*)(filt16 + (size_t)(f0 + col)*KC3 + kt*64 + sh*8);
            *(uint4*)&Bs[col*72 + sh*8] = bv;
        }
        __syncthreads();
        #pragma unroll
        for (int kc = 0; kc < 2; ++kc) {
            int ko = kc*32 + (lane >> 4)*8;
            bf16x8 a0 = *(const bf16x8*)&As[(qm + (lane & 15))*72 + ko];
            bf16x8 a1 = *(const bf16x8*)&As[(qm + 16 + (lane & 15))*72 + ko];
            bf16x8 b0 = *(const bf16x8*)&Bs[(fn + (lane & 15))*72 + ko];
            bf16x8 b1 = *(const bf16x8*)&Bs[(fn + 16 + (lane & 15))*72 + ko];
            acc00 = __builtin_amdgcn_mfma_f32_16x16x32_bf16(a0, b0, acc00, 0, 0, 0);
            acc01 = __builtin_amdgcn_mfma_f32_16x16x32_bf16(a0, b1, acc01, 0, 0, 0);
            acc10 = __builtin_amdgcn_mfma_f32_16x16x32_bf16(a1, b0, acc10, 0, 0, 0);
            acc11 = __builtin_amdgcn_mfma_f32_16x16x32_bf16(a1, b1, acc11, 0, 0, 0);
        }
        __syncthreads();
    }
    /* epilogue: D row=(lane>>4)*4+reg (m-dim), col=lane&15 (n-dim=f) */
    int mb = m0 + qm + (lane >> 4) * 4;
    int fb = f0 + fn + (lane & 15);
    #pragma unroll
    for (int r = 0; r < 4; ++r) {
        int r0 = mb + r;
        if (r0 < MP) {
            conv16[(size_t)r0*NF + fb]        = f2bf(acc00[r]);
            conv16[(size_t)r0*NF + fb + 16]   = f2bf(acc01[r]);
        }
        int r1 = mb + 16 + r;
        if (r1 < MP) {
            conv16[(size_t)r1*NF + fb]        = f2bf(acc10[r]);
            conv16[(size_t)r1*NF + fb + 16]   = f2bf(acc11[r]);
        }
    }
}

/* ---- Kernel 4: conv row norms from bf16 conv ---- */
__global__ void convnorm16_kernel(float* __restrict__ ws) {
    const ushort* conv16 = (const ushort*)(ws + F_CONV16);
    int w = threadIdx.x >> 6, lane = threadIdx.x & 63;
    int r = blockIdx.x*4 + w;
    if (r >= RT) return;
    ushort4 v = *(const ushort4*)(conv16 + (size_t)r*NF + lane*4);
    float a = bf2f(v.x), b = bf2f(v.y), c = bf2f(v.z), d = bf2f(v.w);
    float ss = a*a + b*b + c*c + d*d;
    #pragma unroll
    for (int off = 32; off; off >>= 1) ss += __shfl_xor(ss, off, 64);
    if (lane == 0) ws[F_NC + r] = sqrtf(ss);
}

/* ---- Kernel 5: raw dot matrices via MFMA. grid 200 x 512 (8 waves) ----
   Di[n][q(32)][s(64)] over K=320 emb; Ds[...] over K=256 conv. */
__global__ __launch_bounds__(512)
void sim16_kernel(const float* __restrict__ ws_c, float* __restrict__ ws) {
    const ushort* rows16 = (const ushort*)(ws_c + F_ROWS16);
    const ushort* conv16 = (const ushort*)(ws_c + F_CONV16);
    int n = blockIdx.x;
    int tid = threadIdx.x;
    int lane = tid & 63, w = tid >> 6;
    int qb = (w & 1) * 16;          /* q-tile: 0 or 16 */
    int sb = (w >> 1) * 16;         /* s-tile: 0,16,32,48 */
    int m = lane & 15, h = lane >> 4;

    /* insens: Q rows at RS.., S rows at n*64.. , stride 320 */
    {
        const ushort* Q = rows16 + (size_t)(RS)*KQ;
        const ushort* S = rows16 + (size_t)(n*LS)*KQ;
        f32x4 acc = {};
        #pragma unroll
        for (int kc = 0; kc < 10; ++kc) {
            int ko = kc*32 + h*8;
            bf16x8 a = *(const bf16x8*)(Q + (size_t)(qb + m)*KQ + ko);
            bf16x8 b = *(const bf16x8*)(S + (size_t)(sb + m)*KQ + ko);
            acc = __builtin_amdgcn_mfma_f32_16x16x32_bf16(a, b, acc, 0, 0, 0);
        }
        float* Di = ws + F_DI + (size_t)n*2048;
        #pragma unroll
        for (int r = 0; r < 4; ++r)
            Di[(qb + h*4 + r)*64 + sb + m] = acc[r];
    }
    /* sens: conv rows, stride 256 */
    {
        const ushort* Q = conv16 + (size_t)(RS)*NF;
        const ushort* S = conv16 + (size_t)(n*LS)*NF;
        f32x4 acc = {};
        #pragma unroll
        for (int kc = 0; kc < 8; ++kc) {
            int ko = kc*32 + h*8;
            bf16x8 a = *(const bf16x8*)(Q + (size_t)(qb + m)*NF + ko);
            bf16x8 b = *(const bf16x8*)(S + (size_t)(sb + m)*NF + ko);
            acc = __builtin_amdgcn_mfma_f32_16x16x32_bf16(a, b, acc, 0, 0, 0);
        }
        float* Ds = ws + F_DS + (size_t)n*2048;
        #pragma unroll
        for (int r = 0; r < 4; ++r)
            Ds[(qb + h*4 + r)*64 + sb + m] = acc[r];
    }
}

/* ---- top-5 pool over 64 lanes ---- */
__device__ inline void pool64(float v, float& mx, float& mean5) {
    int lane = threadIdx.x & 63;
    float sum = 0.f;
    mx = 0.f;
    #pragma unroll
    for (int it = 0; it < TOPK; ++it) {
        float m = v; int ml = lane;
        #pragma unroll
        for (int off = 32; off; off >>= 1) {
            float ov = __shfl_xor(m, off, 64);
            int ol = __shfl_xor(ml, off, 64);
            if (ov > m || (ov == m && ol < ml)) { m = ov; ml = ol; }
        }
        if (it == 0) mx = m;
        sum += m;
        if (lane == ml) v = -INFINITY;
    }
    mean5 = sum * (1.f/TOPK);
}

/* ---- Kernel 6: normalize + pool + sigmoid + per-sentence mean ----
   grid NS x 256 (4 waves). Wave w handles q = it*4+w. */
__global__ __launch_bounds__(256)
void pool_kernel(const float* __restrict__ ws_c,
                 const float* __restrict__ dsim,
                 const float* __restrict__ lin_w,
                 const float* __restrict__ lin_b,
                 float* __restrict__ ws,
                 float* __restrict__ out) {
    __shared__ float sred[4];
    int n = blockIdx.x;
    int tid = threadIdx.x;
    int lane = tid & 63, w = tid >> 6;
    const float* Di = ws_c + F_DI + (size_t)n*2048;
    const float* Ds = ws_c + F_DS + (size_t)n*2048;
    float nes = ws_c[F_NE + n*LS + lane];
    float ncs = ws_c[F_NC + n*LS + lane];
    float mks = ws_c[F_MK + n*LS + lane];
    float w0 = lin_w[0], w1 = lin_w[1], w2 = lin_w[2],
          w3 = lin_w[3], w4 = lin_w[4], w5 = lin_w[5], bb = lin_b[0];
    float wsum = 0.f;
    for (int it = 0; it < 8; ++it) {
        int q = it*4 + w;
        if (q < LQ) {
            float neq = ws_c[F_NE + RS + q];
            float ncq = ws_c[F_NC + RS + q];
            float mkq = ws_c[F_MK + RS + q];
            float si = Di[q*64 + lane] / (neq * nes) * (mks * mkq);
            float sc = Ds[q*64 + lane] / (ncq * ncs);
            float so = dsim[(size_t)(n*LS + lane)*LQ + q];
            float f0,f1,f2,f3,f4,f5;
            pool64(si, f0, f1);
            pool64(sc, f2, f3);
            pool64(so, f4, f5);
            if (lane == 0) {
                float z = bb + f0*w0 + f1*w1 + f2*w2 + f3*w3 + f4*w4 + f5*w5;
                wsum += 1.f / (1.f + expf(-z));
            }
        }
    }
    if (lane == 0) sred[w] = wsum;
    __syncthreads();
    if (tid == 0) {
        float s = (sred[0] + sred[1] + sred[2] + sred[3]) * (1.f/LQ);
        out[1 + n] = s;
        ws[F_SENT + n] = s;
    }
}

/* ---- Kernel 7: doc mean ---- */
__global__ void final_kernel(const float* __restrict__ ws, float* __restrict__ out) {
    __shared__ float red[256];
    int tid = threadIdx.x;
    red[tid] = (tid < NS) ? ws[F_SENT + tid] : 0.f;
    __syncthreads();
    for (int off = 128; off; off >>= 1) {
        if (tid < off) red[tid] += red[tid + off];
        __syncthreads();
    }
    if (tid == 0) out[0] = red[0] * (1.f/NS);
}

extern "C" void kernel_launch(void* const* d_in, const int* in_sizes, int n_in,
                              void* d_out, int out_size, void* d_ws, size_t ws_size,
                              hipStream_t stream) {
    const float* emb      = (const float*)d_in[0];
    const float* filt     = (const float*)d_in[1];
    const float* lin_w    = (const float*)d_in[2];
    const float* lin_b    = (const float*)d_in[3];
    const int*   question = (const int*)d_in[4];
    const int*   sents    = (const int*)d_in[5];
    const float* dsim     = (const float*)d_in[6];
    float* ws  = (float*)d_ws;
    float* out = (float*)d_out;

    gather16_kernel<<<MP, 64, 0, stream>>>(emb, question, sents, ws);
    filt16_kernel<<<NF, 64, 0, stream>>>(filt, ws);
    conv16_gemm_kernel<<<dim3(201, 4), 256, 0, stream>>>(ws, ws);
    convnorm16_kernel<<<(RT + 3)/4, 256, 0, stream>>>(ws);
    sim16_kernel<<<NS, 512, 0, stream>>>(ws, ws);
    pool_kernel<<<NS, 256, 0, stream>>>(ws, dsim, lin_w, lin_b, ws, out);
    final_kernel<<<1, 256, 0, stream>>>(ws, out);
}